// Round 19
// baseline (51.614 us; speedup 1.0000x reference)
//
#include <hip/hip_runtime.h>
#include <math.h>
#include <stdint.h>

#define NB 16
#define S1 128
#define S2 192
#define HH 256   // half hidden
#define PP 4
#define FULLH 512
#define EPSV 1e-8f

typedef float f32x4 __attribute__((ext_vector_type(4)));
typedef float f32x2 __attribute__((ext_vector_type(2)));
typedef short short8 __attribute__((ext_vector_type(8)));

// ---- workspace layout (float offsets) ----
#define WS_N2    0                 // [32 db][192]
#define WS_N2W   6144              // [32 db][192][4]
#define WS_N1    30720             // [32 db][128]
#define WS_N1W   34816             // [32 db][128][4] (maxpool bank W[2+d])
#define WS_Q2BF  919552            // uint16 frag-major: [32 db][12 jt][8 sg][64][8]
#define WS_Q1BF  2541696           // uint16 frag-major: [32 db][5 v][8 it][8 sg][64][8]

__device__ __forceinline__ float dot4(const float4& a, const float4& b) {
    return a.x * b.x + a.y * b.y + a.z * b.z + a.w * b.w;
}

__device__ __forceinline__ float vdot4(const f32x4& a, const f32x4& b) {
    return a.x * b.x + a.y * b.y + a.z * b.z + a.w * b.w;
}

__device__ __forceinline__ uint16_t f2bf(float x) {
    union { float f; uint32_t u; } a;
    a.f = x;
    uint32_t r = a.u + 0x7FFF + ((a.u >> 16) & 1);  // RNE
    return (uint16_t)(r >> 16);
}

__device__ __forceinline__ uint32_t pk2(float a, float b) {
    return (uint32_t)f2bf(a) | ((uint32_t)f2bf(b) << 16);
}

template<int N>
__device__ __forceinline__ void wave_reduce_sum_n(float* v) {
#pragma unroll
    for (int m = 1; m < 64; m <<= 1) {
#pragma unroll
        for (int i = 0; i < N; i++) v[i] += __shfl_xor(v[i], m, 64);
    }
}

// norms v3: XCD-PINNED producer mapping (R18 verified). Block bid handles
// 4 rows of db = (bid&7) + 8*((bid>>3)&3). q1-side norms trimmed to the
// 5 values phase A needs (N1X/RVN now computed inline in sapply phase B).
__global__ __launch_bounds__(256) void norms_kernel(const float* __restrict__ q1,
                                                    const float* __restrict__ q2,
                                                    const float* __restrict__ W,
                                                    float* __restrict__ ws) {
    int bid = blockIdx.x;               // 2560 blocks
    int db = (bid & 7) + 8 * ((bid >> 3) & 3);
    int rowchunk = bid >> 5;            // 0..79
    int w = threadIdx.x >> 6;
    int lane = threadIdx.x & 63;
    int r = rowchunk * 4 + w;           // 0..319
    int d = db >> 4;
    int b_ = db & 15;

    int h0 = lane * 4;
    int sg = lane >> 3;
    int khalf = (lane >> 1) & 3;
    int elo = (lane & 1) * 4;
    const float* wmax = W + (size_t)(2 + d) * PP * HH;

    if (r < S2) {
        int j_ = r;
        const float* row = q2 + ((size_t)(b_ * S2 + j_)) * FULLH + d * HH;
        float4 v = *reinterpret_cast<const float4*>(row + h0);

        float s[5];
        s[0] = dot4(v, v);
#pragma unroll
        for (int p = 0; p < PP; p++) {
            float4 wv = *reinterpret_cast<const float4*>(wmax + p * HH + h0);
            float4 t;
            t.x = v.x * wv.x; t.y = v.y * wv.y; t.z = v.z * wv.z; t.w = v.w * wv.w;
            s[1 + p] = dot4(t, t);
        }
        wave_reduce_sum_n<5>(s);
        int nidx = db * S2 + j_;
        if (lane == 0) {
            ws[WS_N2 + nidx] = sqrtf(s[0]);
#pragma unroll
            for (int p = 0; p < PP; p++)
                ws[WS_N2W + (size_t)nidx * PP + p] = sqrtf(s[1 + p]);
        }

        // frag-major bf16 q2 (B-frags)
        uint2 pk;
        pk.x = pk2(v.x, v.y);
        pk.y = pk2(v.z, v.w);
        {
            uint16_t* q2bf = (uint16_t*)(ws + WS_Q2BF) + (size_t)db * (S2 * HH);
            int jt = j_ >> 4, jcol = j_ & 15;
            size_t off = ((size_t)(jt * 8 + sg) * 64 + (khalf << 4) + jcol) * 8 + elo;
            *reinterpret_cast<uint2*>(q2bf + off) = pk;
        }
    } else {
        int i = r - S2;
        int idx = db * S1 + i;
        const float* row = q1 + ((size_t)(b_ * S1 + i)) * FULLH + d * HH;
        float4 v = *reinterpret_cast<const float4*>(row + h0);

        float s[5];
        float4 y[4];   // v * w^2 for bank 2+d (maxpool) -> q1bf variants
        s[0] = dot4(v, v);
#pragma unroll
        for (int p = 0; p < PP; p++) {
            float4 wv = *reinterpret_cast<const float4*>(wmax + p * HH + h0);
            float4 tv;
            tv.x = v.x * wv.x; tv.y = v.y * wv.y;
            tv.z = v.z * wv.z; tv.w = v.w * wv.w;
            s[1 + p] = dot4(tv, tv);
            y[p].x = tv.x * wv.x; y[p].y = tv.y * wv.y;
            y[p].z = tv.z * wv.z; y[p].w = tv.w * wv.w;
        }
        wave_reduce_sum_n<5>(s);
        if (lane == 0) {
            ws[WS_N1 + idx] = sqrtf(s[0]);
#pragma unroll
            for (int p = 0; p < PP; p++)
                ws[WS_N1W + (size_t)idx * PP + p] = sqrtf(s[1 + p]);
        }

        // frag-major q1 variants v0..v4
        uint16_t* q1b5 = (uint16_t*)(ws + WS_Q1BF) + (size_t)db * 163840;
        int itile = i >> 4, icol = i & 15;
        size_t slot = (size_t)((khalf << 4) + icol) * 8 + elo;
        {
            uint2 pk;
            pk.x = pk2(v.x, v.y);
            pk.y = pk2(v.z, v.w);
            size_t so = ((size_t)(0 * 8 + itile) * 8 + sg) * 512 + slot;
            *reinterpret_cast<uint2*>(q1b5 + so) = pk;
        }
#pragma unroll
        for (int p = 0; p < PP; p++) {
            uint2 pk;
            pk.x = pk2(y[p].x, y[p].y);
            pk.y = pk2(y[p].z, y[p].w);
            size_t so = ((size_t)((p + 1) * 8 + itile) * 8 + sg) * 512 + slot;
            *reinterpret_cast<uint2*>(q1b5 + so) = pk;
        }
    }
}

// Fused S+apply (R18 structure; phase-B epilogue = R12's verified 68-value
// butterfly with q1/rv weighted norms computed inline).
__global__ __launch_bounds__(256) void sapply_kernel(const float* __restrict__ q1,
                                                     const float* __restrict__ q2,
                                                     const float* __restrict__ W,
                                                     const float* __restrict__ ws,
                                                     float* __restrict__ out) {
    __shared__ float att_s[S2][8];     // 6 KB  [j][ii]
    __shared__ float satt_s[4][8];     // [jq][ii]
    __shared__ float mc_s[4][8][4];    // [jq][ii][p]

    int bid = blockIdx.x;
    int xcd = bid & 7;
    int rest = bid >> 3;              // 0..63
    int db = xcd + 8 * (rest & 3);    // pinned per XCD
    int it8 = rest >> 2;              // 0..15
    int d = db >> 4;
    int b = db & 15;
    int itile = it8 >> 1;
    int half = it8 & 1;

    int tid = threadIdx.x;
    int w = tid >> 6;                 // phase A: jq; phase B: i-pair
    int lane = tid & 63;
    int h0 = lane * 4;

    const float* q2b = q2 + (size_t)b * S2 * FULLH + d * HH;

    // ================= phase A: MFMA S + att/satt/mc to LDS =================
    {
        int jq = w;
        const uint16_t* q2bfp = (const uint16_t*)(ws + WS_Q2BF) + (size_t)db * (S2 * HH);
        const uint16_t* q1bfp = (const uint16_t*)(ws + WS_Q1BF) + (size_t)db * 163840;

        f32x4 acc[5][3];
#pragma unroll
        for (int v = 0; v < 5; v++)
#pragma unroll
            for (int jt_i = 0; jt_i < 3; jt_i++) acc[v][jt_i] = (f32x4){0.f, 0.f, 0.f, 0.f};

#pragma unroll
        for (int kc = 0; kc < 4; kc++) {
            short8 Bf[3][2];
#pragma unroll
            for (int jt_i = 0; jt_i < 3; jt_i++)
#pragma unroll
                for (int sl = 0; sl < 2; sl++)
                    Bf[jt_i][sl] = *reinterpret_cast<const short8*>(
                        q2bfp + ((size_t)((jq * 3 + jt_i) * 8 + kc * 2 + sl) * 64 + lane) * 8);
#pragma unroll
            for (int v = 0; v < 5; v++) {
                short8 A0 = *reinterpret_cast<const short8*>(
                    q1bfp + ((size_t)(v * 8 + itile) * 8 + kc * 2 + 0) * 512 + lane * 8);
                short8 A1 = *reinterpret_cast<const short8*>(
                    q1bfp + ((size_t)(v * 8 + itile) * 8 + kc * 2 + 1) * 512 + lane * 8);
#pragma unroll
                for (int jt_i = 0; jt_i < 3; jt_i++) {
                    acc[v][jt_i] = __builtin_amdgcn_mfma_f32_16x16x32_bf16(A0, Bf[jt_i][0], acc[v][jt_i], 0, 0, 0);
                    acc[v][jt_i] = __builtin_amdgcn_mfma_f32_16x16x32_bf16(A1, Bf[jt_i][1], acc[v][jt_i], 0, 0, 0);
                }
            }
        }

        // epilogue: C layout col = lane&15 (j), row = (lane>>4)*4 + reg (i)
        int lhi = lane >> 4;
        int lcol = lane & 15;
        bool keep = (lhi >> 1) == half;   // this block keeps 8 of the 16 rows
        int ii0 = (lhi & 1) * 4;          // row offset within kept 8
        int nbase = db * S2;
        int q1b_ = db * S1 + itile * 16 + lhi * 4;

        float n1v[4], n1wc[4][4];
#pragma unroll
        for (int rr = 0; rr < 4; rr++) {
            n1v[rr] = ws[WS_N1 + q1b_ + rr];
#pragma unroll
            for (int p = 0; p < 4; p++)
                n1wc[rr][p] = fmaxf(ws[WS_N1W + (size_t)(q1b_ + rr) * 4 + p], EPSV);
        }

        float satt_acc[4] = {0.f, 0.f, 0.f, 0.f};
        float mc_acc[4][4];
#pragma unroll
        for (int p = 0; p < 4; p++)
#pragma unroll
            for (int rr = 0; rr < 4; rr++) mc_acc[p][rr] = -INFINITY;

#pragma unroll
        for (int jt_i = 0; jt_i < 3; jt_i++) {
            int j = (jq * 3 + jt_i) * 16 + lcol;
            float n2 = ws[WS_N2 + nbase + j];
            float avv[4];
#pragma unroll
            for (int rr = 0; rr < 4; rr++) {
                float den = n1v[rr] * n2;
                avv[rr] = acc[0][jt_i][rr] / (den > EPSV ? den : EPSV);
                satt_acc[rr] += avv[rr];
            }
            if (keep) {
                float4 av;
                av.x = avv[0]; av.y = avv[1]; av.z = avv[2]; av.w = avv[3];
                *reinterpret_cast<float4*>(&att_s[j][ii0]) = av;
            }
#pragma unroll
            for (int p = 0; p < 4; p++) {
                float n2wv = fmaxf(ws[WS_N2W + (size_t)(nbase + j) * 4 + p], EPSV);
#pragma unroll
                for (int rr = 0; rr < 4; rr++) {
                    float cosv = acc[p + 1][jt_i][rr] / (n1wc[rr][p] * n2wv);
                    mc_acc[p][rr] = fmaxf(mc_acc[p][rr], cosv);
                }
            }
        }

        // reduce over the 16 column lanes (stays within each lhi group)
#pragma unroll
        for (int m = 1; m < 16; m <<= 1) {
#pragma unroll
            for (int rr = 0; rr < 4; rr++) satt_acc[rr] += __shfl_xor(satt_acc[rr], m, 64);
#pragma unroll
            for (int p = 0; p < 4; p++)
#pragma unroll
                for (int rr = 0; rr < 4; rr++)
                    mc_acc[p][rr] = fmaxf(mc_acc[p][rr], __shfl_xor(mc_acc[p][rr], m, 64));
        }
        if (keep && lcol == 0) {
#pragma unroll
            for (int rr = 0; rr < 4; rr++) {
                satt_s[jq][ii0 + rr] = satt_acc[rr];
#pragma unroll
                for (int p = 0; p < 4; p++)
                    mc_s[jq][ii0 + rr][p] = mc_acc[p][rr];
            }
        }
    }
    __syncthreads();

    // ================= phase B: apply for i = it8*8 + 2w + {0,1} =================
    {
        int il0 = w * 2;                      // ii of first i
        int i0 = it8 * 8 + il0;

        f32x4 macc0 = (f32x4){0.f, 0.f, 0.f, 0.f};
        f32x4 macc1 = (f32x4){0.f, 0.f, 0.f, 0.f};
        f32x4 mx0 = (f32x4){-INFINITY, -INFINITY, -INFINITY, -INFINITY};
        f32x4 mx1 = (f32x4){-INFINITY, -INFINITY, -INFINITY, -INFINITY};

#pragma unroll 8
        for (int j = 0; j < S2; j++) {
            f32x4 qv = *reinterpret_cast<const f32x4*>(q2b + (size_t)j * FULLH + h0);
            f32x2 a2 = *reinterpret_cast<const f32x2*>(&att_s[j][il0]);
            f32x4 a0 = (f32x4){a2.x, a2.x, a2.x, a2.x};
            f32x4 a1 = (f32x4){a2.y, a2.y, a2.y, a2.y};
            macc0 = __builtin_elementwise_fma(a0, qv, macc0);
            macc1 = __builtin_elementwise_fma(a1, qv, macc1);
            mx0 = __builtin_elementwise_max(mx0, a0 * qv);
            mx1 = __builtin_elementwise_max(mx1, a1 * qv);
        }

        float satt0 = satt_s[0][il0] + satt_s[1][il0] + satt_s[2][il0] + satt_s[3][il0];
        float satt1 = satt_s[0][il0 + 1] + satt_s[1][il0 + 1] +
                      satt_s[2][il0 + 1] + satt_s[3][il0 + 1];
        float sden0 = satt0 > EPSV ? satt0 : EPSV;
        float sden1 = satt1 > EPSV ? satt1 : EPSV;

        // maxpool outputs: lanes 0-7 (ii = lane>>2, p = lane&3)
        if (lane < 8) {
            int iw = il0 + (lane >> 2);
            int p = lane & 3;
            float m = fmaxf(fmaxf(mc_s[0][iw][p], mc_s[1][iw][p]),
                            fmaxf(mc_s[2][iw][p], mc_s[3][iw][p]));
            out[((size_t)(b * S1 + it8 * 8 + iw)) * 32 + 8 + 4 * d + p] = m;
        }

        f32x4 mean0 = macc0 * (1.0f / sden0);
        f32x4 mean1 = macc1 * (1.0f / sden1);
        f32x4 rv = *reinterpret_cast<const f32x4*>(
            q2b + (d == 0 ? (size_t)(S2 - 1) * FULLH : (size_t)0) + h0);
        f32x4 q1v0 = *reinterpret_cast<const f32x4*>(
            q1 + ((size_t)(b * S1 + i0)) * FULLH + d * HH + h0);
        f32x4 q1v1 = *reinterpret_cast<const f32x4*>(
            q1 + ((size_t)(b * S1 + i0 + 1)) * FULLH + d * HH + h0);

        f32x4 q1rv0 = q1v0 * rv, q1me0 = q1v0 * mean0, me20 = mean0 * mean0;
        f32x4 q1mx0 = q1v0 * mx0, mx20 = mx0 * mx0;
        f32x4 q1sq0 = q1v0 * q1v0;
        f32x4 q1rv1 = q1v1 * rv, q1me1 = q1v1 * mean1, me21 = mean1 * mean1;
        f32x4 q1mx1 = q1v1 * mx1, mx21 = mx1 * mx1;
        f32x4 q1sq1 = q1v1 * q1v1;
        f32x4 rv2 = rv * rv;

        // s[ii*32 + p*8 + {0:full-num,1:att-num,2:mean2,3:max-num,4:mx2,
        //                  5:q1w2f,6:q1w2a,7:q1w2m}]; s[64+p] = rv2w2f
        float s[68];
#pragma unroll
        for (int p = 0; p < 4; p++) {
            f32x4 wf = *reinterpret_cast<const f32x4*>(W + ((size_t)d * PP + p) * HH + h0);
            f32x4 wa = *reinterpret_cast<const f32x4*>(W + ((size_t)(4 + d) * PP + p) * HH + h0);
            f32x4 wm = *reinterpret_cast<const f32x4*>(W + ((size_t)(6 + d) * PP + p) * HH + h0);
            f32x4 w2f = wf * wf, w2a = wa * wa, w2m = wm * wm;
            s[p * 8 + 0] = vdot4(q1rv0, w2f);
            s[p * 8 + 1] = vdot4(q1me0, w2a);
            s[p * 8 + 2] = vdot4(me20, w2a);
            s[p * 8 + 3] = vdot4(q1mx0, w2m);
            s[p * 8 + 4] = vdot4(mx20, w2m);
            s[p * 8 + 5] = vdot4(q1sq0, w2f);
            s[p * 8 + 6] = vdot4(q1sq0, w2a);
            s[p * 8 + 7] = vdot4(q1sq0, w2m);
            s[32 + p * 8 + 0] = vdot4(q1rv1, w2f);
            s[32 + p * 8 + 1] = vdot4(q1me1, w2a);
            s[32 + p * 8 + 2] = vdot4(me21, w2a);
            s[32 + p * 8 + 3] = vdot4(q1mx1, w2m);
            s[32 + p * 8 + 4] = vdot4(mx21, w2m);
            s[32 + p * 8 + 5] = vdot4(q1sq1, w2f);
            s[32 + p * 8 + 6] = vdot4(q1sq1, w2a);
            s[32 + p * 8 + 7] = vdot4(q1sq1, w2m);
            s[64 + p] = vdot4(rv2, w2f);
        }
        wave_reduce_sum_n<68>(s);

        if (lane == 0) {
#pragma unroll
            for (int ii = 0; ii < 2; ii++) {
                int i = i0 + ii;
                size_t obase = ((size_t)(b * S1 + i)) * 32;
#pragma unroll
                for (int p = 0; p < 4; p++) {
                    const float* sp = s + ii * 32 + p * 8;
                    float rvn = fmaxf(sqrtf(s[64 + p]), EPSV);
                    float nf = fmaxf(sqrtf(sp[5]), EPSV);
                    float na = fmaxf(sqrtf(sp[6]), EPSV);
                    float nm = fmaxf(sqrtf(sp[7]), EPSV);
                    out[obase + 0 + 4 * d + p] = sp[0] / (nf * rvn);
                    out[obase + 16 + 4 * d + p] = sp[1] / (na * fmaxf(sqrtf(sp[2]), EPSV));
                    out[obase + 24 + 4 * d + p] = sp[3] / (nm * fmaxf(sqrtf(sp[4]), EPSV));
                }
            }
        }
    }
}

extern "C" void kernel_launch(void* const* d_in, const int* in_sizes, int n_in,
                              void* d_out, int out_size, void* d_ws, size_t ws_size,
                              hipStream_t stream) {
    const float* q1 = (const float*)d_in[0];
    const float* q2 = (const float*)d_in[1];
    const float* W = (const float*)d_in[2];
    float* out = (float*)d_out;
    float* ws = (float*)d_ws;

    norms_kernel<<<dim3(2560), dim3(256), 0, stream>>>(q1, q2, W, ws);

    sapply_kernel<<<dim3(512), dim3(256), 0, stream>>>(q1, q2, W, ws, out);
}

// Round 20
// 47.261 us; speedup vs baseline: 1.0921x; 1.0921x over previous
//
#include <hip/hip_runtime.h>
#include <math.h>
#include <stdint.h>

#define NB 16
#define S1 128
#define S2 192
#define HH 256   // half hidden
#define PP 4
#define FULLH 512
#define EPSV 1e-8f

typedef float f32x4 __attribute__((ext_vector_type(4)));
typedef float f32x2 __attribute__((ext_vector_type(2)));
typedef short short8 __attribute__((ext_vector_type(8)));

// ---- workspace layout (float offsets) ----
#define WS_N2    0                 // [32 db][192]
#define WS_N2W   6144              // [32 db][192][4]
#define WS_N1    30720             // [32 db][128]
#define WS_N1W   34816             // [32 db][128][4] (maxpool bank W[2+d])
#define WS_Q2BF  919552            // uint16 frag-major: [32 db][12 jt][8 sg][64][8]
#define WS_N1X   2492416           // [4096][12]: q1 norms for banks W[d],W[4+d],W[6+d]
#define WS_RVN   2541568           // [32 db][4]: rv norms with W[d]
#define WS_Q1BF  2541696           // uint16 frag-major: [32 db][5 v][8 it][8 sg][64][8]

__device__ __forceinline__ float dot4(const float4& a, const float4& b) {
    return a.x * b.x + a.y * b.y + a.z * b.z + a.w * b.w;
}

__device__ __forceinline__ float vdot4(const f32x4& a, const f32x4& b) {
    return a.x * b.x + a.y * b.y + a.z * b.z + a.w * b.w;
}

__device__ __forceinline__ uint16_t f2bf(float x) {
    union { float f; uint32_t u; } a;
    a.f = x;
    uint32_t r = a.u + 0x7FFF + ((a.u >> 16) & 1);  // RNE
    return (uint16_t)(r >> 16);
}

__device__ __forceinline__ uint32_t pk2(float a, float b) {
    return (uint32_t)f2bf(a) | ((uint32_t)f2bf(b) << 16);
}

template<int N>
__device__ __forceinline__ void wave_reduce_sum_n(float* v) {
#pragma unroll
    for (int m = 1; m < 64; m <<= 1) {
#pragma unroll
        for (int i = 0; i < N; i++) v[i] += __shfl_xor(v[i], m, 64);
    }
}

// norms v2 (R18 verified): XCD-PINNED producer mapping. Block bid handles
// 4 rows of db = (bid&7) + 8*((bid>>3)&3) — the same XCD that sapply reads
// db from. Rows 0..191 = q2 row j; rows 192..319 = q1 row i.
__global__ __launch_bounds__(256) void norms_kernel(const float* __restrict__ q1,
                                                    const float* __restrict__ q2,
                                                    const float* __restrict__ W,
                                                    float* __restrict__ ws) {
    int bid = blockIdx.x;               // 2560 blocks
    int db = (bid & 7) + 8 * ((bid >> 3) & 3);
    int rowchunk = bid >> 5;            // 0..79
    int w = threadIdx.x >> 6;
    int lane = threadIdx.x & 63;
    int r = rowchunk * 4 + w;           // 0..319
    int d = db >> 4;
    int b_ = db & 15;

    int h0 = lane * 4;
    int sg = lane >> 3;
    int khalf = (lane >> 1) & 3;
    int elo = (lane & 1) * 4;

    if (r < S2) {
        int j_ = r;
        const float* row = q2 + ((size_t)(b_ * S2 + j_)) * FULLH + d * HH;
        float4 v = *reinterpret_cast<const float4*>(row + h0);
        const float* wmax = W + (size_t)(2 + d) * PP * HH;

        float s[5];
        s[0] = dot4(v, v);
#pragma unroll
        for (int p = 0; p < PP; p++) {
            float4 wv = *reinterpret_cast<const float4*>(wmax + p * HH + h0);
            float4 t;
            t.x = v.x * wv.x; t.y = v.y * wv.y; t.z = v.z * wv.z; t.w = v.w * wv.w;
            s[1 + p] = dot4(t, t);
        }
        wave_reduce_sum_n<5>(s);
        int nidx = db * S2 + j_;
        if (lane == 0) {
            ws[WS_N2 + nidx] = sqrtf(s[0]);
#pragma unroll
            for (int p = 0; p < PP; p++)
                ws[WS_N2W + (size_t)nidx * PP + p] = sqrtf(s[1 + p]);
        }

        // rv rows: extra norms with W[d]
        if ((d == 0 && j_ == S2 - 1) || (d == 1 && j_ == 0)) {
            float e[4];
#pragma unroll
            for (int p = 0; p < PP; p++) {
                float4 wv = *reinterpret_cast<const float4*>(W + ((size_t)d * PP + p) * HH + h0);
                float4 t;
                t.x = v.x * wv.x; t.y = v.y * wv.y; t.z = v.z * wv.z; t.w = v.w * wv.w;
                e[p] = dot4(t, t);
            }
            wave_reduce_sum_n<4>(e);
            if (lane == 0) {
#pragma unroll
                for (int p = 0; p < PP; p++)
                    ws[WS_RVN + db * 4 + p] = sqrtf(e[p]);
            }
        }

        // frag-major bf16 q2 (B-frags)
        uint2 pk;
        pk.x = pk2(v.x, v.y);
        pk.y = pk2(v.z, v.w);
        {
            uint16_t* q2bf = (uint16_t*)(ws + WS_Q2BF) + (size_t)db * (S2 * HH);
            int jt = j_ >> 4, jcol = j_ & 15;
            size_t off = ((size_t)(jt * 8 + sg) * 64 + (khalf << 4) + jcol) * 8 + elo;
            *reinterpret_cast<uint2*>(q2bf + off) = pk;
        }
    } else {
        int i = r - S2;
        int idx = db * S1 + i;
        const float* row = q1 + ((size_t)(b_ * S1 + i)) * FULLH + d * HH;
        float4 v = *reinterpret_cast<const float4*>(row + h0);

        int banks[4] = {2 + d, d, 4 + d, 6 + d};
        float s[17];
        float4 y[4];   // v * w^2 for bank 2+d (maxpool) -> q1bf variants
        s[0] = dot4(v, v);
#pragma unroll
        for (int t = 0; t < 4; t++) {
#pragma unroll
            for (int p = 0; p < PP; p++) {
                float4 wv = *reinterpret_cast<const float4*>(
                    W + ((size_t)banks[t] * PP + p) * HH + h0);
                float4 tv;
                tv.x = v.x * wv.x; tv.y = v.y * wv.y;
                tv.z = v.z * wv.z; tv.w = v.w * wv.w;
                s[1 + t * 4 + p] = dot4(tv, tv);
                if (t == 0) {
                    y[p].x = tv.x * wv.x; y[p].y = tv.y * wv.y;
                    y[p].z = tv.z * wv.z; y[p].w = tv.w * wv.w;
                }
            }
        }
        wave_reduce_sum_n<17>(s);
        if (lane == 0) {
            ws[WS_N1 + idx] = sqrtf(s[0]);
#pragma unroll
            for (int p = 0; p < PP; p++)
                ws[WS_N1W + (size_t)idx * PP + p] = sqrtf(s[1 + p]);
#pragma unroll
            for (int t = 0; t < 3; t++)
#pragma unroll
                for (int p = 0; p < PP; p++)
                    ws[WS_N1X + (size_t)idx * 12 + t * 4 + p] = sqrtf(s[5 + t * 4 + p]);
        }

        // frag-major q1 variants v0..v4
        uint16_t* q1b5 = (uint16_t*)(ws + WS_Q1BF) + (size_t)db * 163840;
        int itile = i >> 4, icol = i & 15;
        size_t slot = (size_t)((khalf << 4) + icol) * 8 + elo;
        {
            uint2 pk;
            pk.x = pk2(v.x, v.y);
            pk.y = pk2(v.z, v.w);
            size_t so = ((size_t)(0 * 8 + itile) * 8 + sg) * 512 + slot;
            *reinterpret_cast<uint2*>(q1b5 + so) = pk;
        }
#pragma unroll
        for (int p = 0; p < PP; p++) {
            uint2 pk;
            pk.x = pk2(y[p].x, y[p].y);
            pk.y = pk2(y[p].z, y[p].w);
            size_t so = ((size_t)((p + 1) * 8 + itile) * 8 + sg) * 512 + slot;
            *reinterpret_cast<uint2*>(q1b5 + so) = pk;
        }
    }
}

// Fused S+apply (R13/R18-verified): block = (db, it8 of 8 i's); 512 blocks x
// 4 waves. Phase A: wave jq computes MFMA S for itile=it8>>1, keeps its 8
// rows; att/satt/mc -> LDS. Phase B: wave w streams f32 q2 for
// i = it8*8 + 2w + {0,1}; 40-value butterfly finishes 24 outputs.
__global__ __launch_bounds__(256) void sapply_kernel(const float* __restrict__ q1,
                                                     const float* __restrict__ q2,
                                                     const float* __restrict__ W,
                                                     const float* __restrict__ ws,
                                                     float* __restrict__ out) {
    __shared__ float att_s[S2][8];     // 6 KB  [j][ii]
    __shared__ float satt_s[4][8];     // [jq][ii]
    __shared__ float mc_s[4][8][4];    // [jq][ii][p]

    int bid = blockIdx.x;
    int xcd = bid & 7;
    int rest = bid >> 3;              // 0..63
    int db = xcd + 8 * (rest & 3);    // pinned per XCD
    int it8 = rest >> 2;              // 0..15
    int d = db >> 4;
    int b = db & 15;
    int itile = it8 >> 1;
    int half = it8 & 1;

    int tid = threadIdx.x;
    int w = tid >> 6;                 // phase A: jq; phase B: i-pair
    int lane = tid & 63;
    int h0 = lane * 4;

    const float* q2b = q2 + (size_t)b * S2 * FULLH + d * HH;

    // ================= phase A: MFMA S + att/satt/mc to LDS =================
    {
        int jq = w;
        const uint16_t* q2bfp = (const uint16_t*)(ws + WS_Q2BF) + (size_t)db * (S2 * HH);
        const uint16_t* q1bfp = (const uint16_t*)(ws + WS_Q1BF) + (size_t)db * 163840;

        f32x4 acc[5][3];
#pragma unroll
        for (int v = 0; v < 5; v++)
#pragma unroll
            for (int jt_i = 0; jt_i < 3; jt_i++) acc[v][jt_i] = (f32x4){0.f, 0.f, 0.f, 0.f};

#pragma unroll
        for (int kc = 0; kc < 4; kc++) {
            short8 Bf[3][2];
#pragma unroll
            for (int jt_i = 0; jt_i < 3; jt_i++)
#pragma unroll
                for (int sl = 0; sl < 2; sl++)
                    Bf[jt_i][sl] = *reinterpret_cast<const short8*>(
                        q2bfp + ((size_t)((jq * 3 + jt_i) * 8 + kc * 2 + sl) * 64 + lane) * 8);
#pragma unroll
            for (int v = 0; v < 5; v++) {
                short8 A0 = *reinterpret_cast<const short8*>(
                    q1bfp + ((size_t)(v * 8 + itile) * 8 + kc * 2 + 0) * 512 + lane * 8);
                short8 A1 = *reinterpret_cast<const short8*>(
                    q1bfp + ((size_t)(v * 8 + itile) * 8 + kc * 2 + 1) * 512 + lane * 8);
#pragma unroll
                for (int jt_i = 0; jt_i < 3; jt_i++) {
                    acc[v][jt_i] = __builtin_amdgcn_mfma_f32_16x16x32_bf16(A0, Bf[jt_i][0], acc[v][jt_i], 0, 0, 0);
                    acc[v][jt_i] = __builtin_amdgcn_mfma_f32_16x16x32_bf16(A1, Bf[jt_i][1], acc[v][jt_i], 0, 0, 0);
                }
            }
        }

        // epilogue: C layout col = lane&15 (j), row = (lane>>4)*4 + reg (i)
        int lhi = lane >> 4;
        int lcol = lane & 15;
        bool keep = (lhi >> 1) == half;   // this block keeps 8 of the 16 rows
        int ii0 = (lhi & 1) * 4;          // row offset within kept 8
        int nbase = db * S2;
        int q1b_ = db * S1 + itile * 16 + lhi * 4;

        float n1v[4], n1wc[4][4];
#pragma unroll
        for (int rr = 0; rr < 4; rr++) {
            n1v[rr] = ws[WS_N1 + q1b_ + rr];
#pragma unroll
            for (int p = 0; p < 4; p++)
                n1wc[rr][p] = fmaxf(ws[WS_N1W + (size_t)(q1b_ + rr) * 4 + p], EPSV);
        }

        float satt_acc[4] = {0.f, 0.f, 0.f, 0.f};
        float mc_acc[4][4];
#pragma unroll
        for (int p = 0; p < 4; p++)
#pragma unroll
            for (int rr = 0; rr < 4; rr++) mc_acc[p][rr] = -INFINITY;

#pragma unroll
        for (int jt_i = 0; jt_i < 3; jt_i++) {
            int j = (jq * 3 + jt_i) * 16 + lcol;
            float n2 = ws[WS_N2 + nbase + j];
            float avv[4];
#pragma unroll
            for (int rr = 0; rr < 4; rr++) {
                float den = n1v[rr] * n2;
                avv[rr] = acc[0][jt_i][rr] / (den > EPSV ? den : EPSV);
                satt_acc[rr] += avv[rr];
            }
            if (keep) {
                float4 av;
                av.x = avv[0]; av.y = avv[1]; av.z = avv[2]; av.w = avv[3];
                *reinterpret_cast<float4*>(&att_s[j][ii0]) = av;
            }
#pragma unroll
            for (int p = 0; p < 4; p++) {
                float n2wv = fmaxf(ws[WS_N2W + (size_t)(nbase + j) * 4 + p], EPSV);
#pragma unroll
                for (int rr = 0; rr < 4; rr++) {
                    float cosv = acc[p + 1][jt_i][rr] / (n1wc[rr][p] * n2wv);
                    mc_acc[p][rr] = fmaxf(mc_acc[p][rr], cosv);
                }
            }
        }

        // reduce over the 16 column lanes (stays within each lhi group)
#pragma unroll
        for (int m = 1; m < 16; m <<= 1) {
#pragma unroll
            for (int rr = 0; rr < 4; rr++) satt_acc[rr] += __shfl_xor(satt_acc[rr], m, 64);
#pragma unroll
            for (int p = 0; p < 4; p++)
#pragma unroll
                for (int rr = 0; rr < 4; rr++)
                    mc_acc[p][rr] = fmaxf(mc_acc[p][rr], __shfl_xor(mc_acc[p][rr], m, 64));
        }
        if (keep && lcol == 0) {
#pragma unroll
            for (int rr = 0; rr < 4; rr++) {
                satt_s[jq][ii0 + rr] = satt_acc[rr];
#pragma unroll
                for (int p = 0; p < 4; p++)
                    mc_s[jq][ii0 + rr][p] = mc_acc[p][rr];
            }
        }
    }
    __syncthreads();

    // ================= phase B: apply for i = it8*8 + 2w + {0,1} =================
    {
        int il0 = w * 2;                      // ii of first i
        int i0 = it8 * 8 + il0;

        f32x4 macc0 = (f32x4){0.f, 0.f, 0.f, 0.f};
        f32x4 macc1 = (f32x4){0.f, 0.f, 0.f, 0.f};
        f32x4 mx0 = (f32x4){-INFINITY, -INFINITY, -INFINITY, -INFINITY};
        f32x4 mx1 = (f32x4){-INFINITY, -INFINITY, -INFINITY, -INFINITY};

#pragma unroll 8
        for (int j = 0; j < S2; j++) {
            f32x4 qv = *reinterpret_cast<const f32x4*>(q2b + (size_t)j * FULLH + h0);
            f32x2 a2 = *reinterpret_cast<const f32x2*>(&att_s[j][il0]);
            f32x4 a0 = (f32x4){a2.x, a2.x, a2.x, a2.x};
            f32x4 a1 = (f32x4){a2.y, a2.y, a2.y, a2.y};
            macc0 = __builtin_elementwise_fma(a0, qv, macc0);
            macc1 = __builtin_elementwise_fma(a1, qv, macc1);
            mx0 = __builtin_elementwise_max(mx0, a0 * qv);
            mx1 = __builtin_elementwise_max(mx1, a1 * qv);
        }

        float satt0 = satt_s[0][il0] + satt_s[1][il0] + satt_s[2][il0] + satt_s[3][il0];
        float satt1 = satt_s[0][il0 + 1] + satt_s[1][il0 + 1] +
                      satt_s[2][il0 + 1] + satt_s[3][il0 + 1];
        float sden0 = satt0 > EPSV ? satt0 : EPSV;
        float sden1 = satt1 > EPSV ? satt1 : EPSV;

        // maxpool outputs: lanes 0-7 (ii = lane>>2, p = lane&3)
        if (lane < 8) {
            int iw = il0 + (lane >> 2);
            int p = lane & 3;
            float m = fmaxf(fmaxf(mc_s[0][iw][p], mc_s[1][iw][p]),
                            fmaxf(mc_s[2][iw][p], mc_s[3][iw][p]));
            out[((size_t)(b * S1 + it8 * 8 + iw)) * 32 + 8 + 4 * d + p] = m;
        }

        f32x4 mean0 = macc0 * (1.0f / sden0);
        f32x4 mean1 = macc1 * (1.0f / sden1);
        f32x4 rv = *reinterpret_cast<const f32x4*>(
            q2b + (d == 0 ? (size_t)(S2 - 1) * FULLH : (size_t)0) + h0);
        f32x4 q1v0 = *reinterpret_cast<const f32x4*>(
            q1 + ((size_t)(b * S1 + i0)) * FULLH + d * HH + h0);
        f32x4 q1v1 = *reinterpret_cast<const f32x4*>(
            q1 + ((size_t)(b * S1 + i0 + 1)) * FULLH + d * HH + h0);

        f32x4 q1rv0 = q1v0 * rv, q1me0 = q1v0 * mean0, me20 = mean0 * mean0;
        f32x4 q1mx0 = q1v0 * mx0, mx20 = mx0 * mx0;
        f32x4 q1rv1 = q1v1 * rv, q1me1 = q1v1 * mean1, me21 = mean1 * mean1;
        f32x4 q1mx1 = q1v1 * mx1, mx21 = mx1 * mx1;

        // s[ii*20 + p*5 + {0:full-num,1:att-num,2:mean2,3:max-num,4:mx2}]
        float s[40];
#pragma unroll
        for (int p = 0; p < 4; p++) {
            f32x4 wf = *reinterpret_cast<const f32x4*>(W + ((size_t)d * PP + p) * HH + h0);
            f32x4 wa = *reinterpret_cast<const f32x4*>(W + ((size_t)(4 + d) * PP + p) * HH + h0);
            f32x4 wm = *reinterpret_cast<const f32x4*>(W + ((size_t)(6 + d) * PP + p) * HH + h0);
            f32x4 w2f = wf * wf, w2a = wa * wa, w2m = wm * wm;
            s[p * 5 + 0] = vdot4(q1rv0, w2f);
            s[p * 5 + 1] = vdot4(q1me0, w2a);
            s[p * 5 + 2] = vdot4(me20, w2a);
            s[p * 5 + 3] = vdot4(q1mx0, w2m);
            s[p * 5 + 4] = vdot4(mx20, w2m);
            s[20 + p * 5 + 0] = vdot4(q1rv1, w2f);
            s[20 + p * 5 + 1] = vdot4(q1me1, w2a);
            s[20 + p * 5 + 2] = vdot4(me21, w2a);
            s[20 + p * 5 + 3] = vdot4(q1mx1, w2m);
            s[20 + p * 5 + 4] = vdot4(mx21, w2m);
        }
        wave_reduce_sum_n<40>(s);

        if (lane == 0) {
#pragma unroll
            for (int ii = 0; ii < 2; ii++) {
                int i = i0 + ii;
                int qi = db * S1 + i;
                size_t obase = ((size_t)(b * S1 + i)) * 32;
                const float* nx = ws + WS_N1X + (size_t)qi * 12;
#pragma unroll
                for (int p = 0; p < 4; p++) {
                    float nf = fmaxf(nx[p], EPSV);
                    float na = fmaxf(nx[4 + p], EPSV);
                    float nm = fmaxf(nx[8 + p], EPSV);
                    float rvn = fmaxf(ws[WS_RVN + db * 4 + p], EPSV);
                    const float* sp = s + ii * 20 + p * 5;
                    out[obase + 0 + 4 * d + p] = sp[0] / (nf * rvn);
                    out[obase + 16 + 4 * d + p] = sp[1] / (na * fmaxf(sqrtf(sp[2]), EPSV));
                    out[obase + 24 + 4 * d + p] = sp[3] / (nm * fmaxf(sqrtf(sp[4]), EPSV));
                }
            }
        }
    }
}

extern "C" void kernel_launch(void* const* d_in, const int* in_sizes, int n_in,
                              void* d_out, int out_size, void* d_ws, size_t ws_size,
                              hipStream_t stream) {
    const float* q1 = (const float*)d_in[0];
    const float* q2 = (const float*)d_in[1];
    const float* W = (const float*)d_in[2];
    float* out = (float*)d_out;
    float* ws = (float*)d_ws;

    norms_kernel<<<dim3(2560), dim3(256), 0, stream>>>(q1, q2, W, ws);

    sapply_kernel<<<dim3(512), dim3(256), 0, stream>>>(q1, q2, W, ws, out);
}